// Round 5
// baseline (282.369 us; speedup 1.0000x reference)
//
#include <hip/hip_runtime.h>

// TargetMLPReadout, bf16x3 split-precision MFMA, multi-batch blocks (gfx950).
// out[b] = colsum_{rows} relu(relu(tpart_b + A_b @ W1bot) @ W2 + b2), tpart = b1 + t_b @ W1top
// x = hi + lo (bf16 RNE); X@Y ~= Xhi@Yhi + Xhi@Ylo + Xlo@Yhi (fp32-grade, proven absmax 0.5).
//
// 512 blocks x 512 thr (8 waves) x GB=8 batches each -> exactly 2 blocks/CU, no tail.
// Per wave: 16-col output slice; B hi-frags (both layers) live in 32 VGPRs (loaded once);
// B lo-frags prefetched from L2 per gemm. A/H staged in LDS hi/lo bf16, XOR swizzle
// byte^=((row&7)<<4). Next batch's A prefetched into regs during current gemms (T14).
// LDS 68.6 KB -> 2 blocks/CU. tpart computed for all 8 batches once per block.

#define DIM   128
#define NODES 64
#define NTN   63
#define GB    8

typedef short bf16x8 __attribute__((ext_vector_type(8)));
typedef float f32x4  __attribute__((ext_vector_type(4)));

static __device__ __forceinline__ unsigned short f2bf(float f) {   // RNE, no NaN inputs
    unsigned int u = __float_as_uint(f);
    u += 0x7FFFu + ((u >> 16) & 1u);
    return (unsigned short)(u >> 16);
}
static __device__ __forceinline__ float bf2f(unsigned short h) {
    return __uint_as_float(((unsigned int)h) << 16);
}

// wt (ushort): layer0=W1bot, layer1=W2; each: hi plane [n][k] 128x128 then lo plane. 128 KB.
__global__ void pack_wt(const float* __restrict__ W1,
                        const float* __restrict__ W2,
                        unsigned short* __restrict__ wt) {
    const int b     = blockIdx.x;        // 0..255
    const int layer = b >> 7;
    const int n     = b & 127;
    const int k     = threadIdx.x;       // 0..127
    const float* W  = layer ? W2 : (W1 + DIM * DIM);
    const float w   = W[k * DIM + n];
    const unsigned short hi = f2bf(w);
    const unsigned short lo = f2bf(w - bf2f(hi));
    unsigned short* base = wt + layer * (2 * DIM * DIM);
    base[n * DIM + k]             = hi;
    base[DIM * DIM + n * DIM + k] = lo;
}

__global__ __launch_bounds__(512, 4)
void mlp_mfma(const float* __restrict__ embs,
              const float* __restrict__ W1,
              const float* __restrict__ b1,
              const float* __restrict__ b2,
              const unsigned short* __restrict__ wt,
              float* __restrict__ out) {
    __shared__ unsigned short sA[2][NODES * DIM];   // 32 KB: A hi/lo, swizzled
    __shared__ unsigned short sH[2][NODES * DIM];   // 32 KB: H1 hi/lo, swizzled
    __shared__ float sT[GB][DIM];                   // 4 KB: tpart per batch

    const int tid = threadIdx.x;
    const int w   = tid >> 6;            // wave 0..7 -> cols [16w, 16w+16)
    const int ln  = tid & 63;
    const int l15 = ln & 15;
    const int g   = ln >> 4;
    const int cw  = w * 16;
    const long bg = (long)blockIdx.x * GB;
    const float* ebase = embs + bg * (NODES * DIM);

    // ---- B hi fragments for both layers: resident in regs for whole block ----
    bf16x8 bh[2][4];
    #pragma unroll
    for (int L = 0; L < 2; ++L)
        #pragma unroll
        for (int kk = 0; kk < 4; ++kk)
            bh[L][kk] = *(const bf16x8*)(wt + L * 2 * DIM * DIM + (cw + l15) * DIM + kk * 32 + g * 8);

    // ---- prefetch batch 0 A rows (nodes 1..63, row 63 zero) into regs ----
    float4 pf0, pf1, pf2, pf3;
    {
        const float* e0 = ebase;
        int Q;
        Q = tid;        pf0 = (Q >> 5) < NTN ? *(const float4*)(e0 + ((Q >> 5) + 1) * DIM + (Q & 31) * 4) : make_float4(0.f, 0.f, 0.f, 0.f);
        Q = tid + 512;  pf1 = (Q >> 5) < NTN ? *(const float4*)(e0 + ((Q >> 5) + 1) * DIM + (Q & 31) * 4) : make_float4(0.f, 0.f, 0.f, 0.f);
        Q = tid + 1024; pf2 = (Q >> 5) < NTN ? *(const float4*)(e0 + ((Q >> 5) + 1) * DIM + (Q & 31) * 4) : make_float4(0.f, 0.f, 0.f, 0.f);
        Q = tid + 1536; pf3 = (Q >> 5) < NTN ? *(const float4*)(e0 + ((Q >> 5) + 1) * DIM + (Q & 31) * 4) : make_float4(0.f, 0.f, 0.f, 0.f);
    }

    // ---- tpart for all GB batches: thread -> (batch bi, col j), fp32 exact ----
    #pragma unroll
    for (int q = 0; q < 2; ++q) {
        const int idx = tid + q * 512;        // 0..1023
        const int bi  = idx >> 7;
        const int j   = idx & 127;
        const float* t = ebase + bi * (NODES * DIM);   // target = node 0
        float p = b1[j];
        #pragma unroll 4
        for (int k = 0; k < DIM; ++k)
            p = fmaf(t[k], W1[k * DIM + j], p);        // W1 top half
        sT[bi][j] = p;
    }

    const float tb2 = b2[cw + l15];

    for (int i = 0; i < GB; ++i) {
        // ---- write prefetched rows (batch i) to sA as hi/lo, swizzled ----
        {
            float4 pv[4] = {pf0, pf1, pf2, pf3};
            #pragma unroll
            for (int qq = 0; qq < 4; ++qq) {
                const int Q   = tid + qq * 512;
                const int row = Q >> 5;
                const int c0  = (Q & 31) * 4;
                const float vf[4] = {pv[qq].x, pv[qq].y, pv[qq].z, pv[qq].w};
                unsigned int hp[2], lp[2];
                #pragma unroll
                for (int e = 0; e < 2; ++e) {
                    const unsigned short h0 = f2bf(vf[2 * e]),     h1 = f2bf(vf[2 * e + 1]);
                    const unsigned short q0 = f2bf(vf[2 * e]     - bf2f(h0));
                    const unsigned short q1 = f2bf(vf[2 * e + 1] - bf2f(h1));
                    hp[e] = (unsigned int)h0 | ((unsigned int)h1 << 16);
                    lp[e] = (unsigned int)q0 | ((unsigned int)q1 << 16);
                }
                const int byt = row * 256 + ((c0 * 2) ^ ((row & 7) << 4));
                *(uint2*)((char*)sA[0] + byt) = make_uint2(hp[0], hp[1]);
                *(uint2*)((char*)sA[1] + byt) = make_uint2(lp[0], lp[1]);
            }
        }
        // ---- issue prefetch for batch i+1 (hides HBM under both gemms) ----
        if (i + 1 < GB) {
            const float* en = ebase + (i + 1) * (NODES * DIM);
            int Q;
            Q = tid;        pf0 = (Q >> 5) < NTN ? *(const float4*)(en + ((Q >> 5) + 1) * DIM + (Q & 31) * 4) : make_float4(0.f, 0.f, 0.f, 0.f);
            Q = tid + 512;  pf1 = (Q >> 5) < NTN ? *(const float4*)(en + ((Q >> 5) + 1) * DIM + (Q & 31) * 4) : make_float4(0.f, 0.f, 0.f, 0.f);
            Q = tid + 1024; pf2 = (Q >> 5) < NTN ? *(const float4*)(en + ((Q >> 5) + 1) * DIM + (Q & 31) * 4) : make_float4(0.f, 0.f, 0.f, 0.f);
            Q = tid + 1536; pf3 = (Q >> 5) < NTN ? *(const float4*)(en + ((Q >> 5) + 1) * DIM + (Q & 31) * 4) : make_float4(0.f, 0.f, 0.f, 0.f);
        }
        __syncthreads();                               // BAR1: sA (+sT on i==0) ready

        // ================= layer 1 =================
        f32x4 acc[4];
        {
            const float t0 = sT[i][cw + l15];
            #pragma unroll
            for (int mi = 0; mi < 4; ++mi) acc[mi] = (f32x4){t0, t0, t0, t0};
        }
        {
            const unsigned short* wlo = wt + DIM * DIM;            // W1bot lo plane
            bf16x8 bl[4];
            #pragma unroll
            for (int kk = 0; kk < 4; ++kk)
                bl[kk] = *(const bf16x8*)(wlo + (cw + l15) * DIM + kk * 32 + g * 8);
            #pragma unroll
            for (int kk = 0; kk < 4; ++kk) {
                const int kb = (kk * 32 + g * 8) * 2;
                #pragma unroll
                for (int mi = 0; mi < 4; ++mi) {
                    const int row = mi * 16 + l15;
                    const int byt = row * 256 + (kb ^ ((row & 7) << 4));
                    const bf16x8 ah = *(const bf16x8*)((const char*)sA[0] + byt);
                    const bf16x8 al = *(const bf16x8*)((const char*)sA[1] + byt);
                    acc[mi] = __builtin_amdgcn_mfma_f32_16x16x32_bf16(ah, bh[0][kk], acc[mi], 0, 0, 0);
                    acc[mi] = __builtin_amdgcn_mfma_f32_16x16x32_bf16(ah, bl[kk],    acc[mi], 0, 0, 0);
                    acc[mi] = __builtin_amdgcn_mfma_f32_16x16x32_bf16(al, bh[0][kk], acc[mi], 0, 0, 0);
                }
            }
        }
        __syncthreads();                               // BAR2: all sA reads done

        // ---- relu -> H1 hi/lo (C layout: col=l15, row=16mi+4g+r) ----
        #pragma unroll
        for (int mi = 0; mi < 4; ++mi)
            #pragma unroll
            for (int r = 0; r < 4; ++r) {
                const int row = mi * 16 + g * 4 + r;
                const int col = cw + l15;
                const float v = fmaxf(acc[mi][r], 0.f);
                const unsigned short h = f2bf(v);
                const unsigned short l = f2bf(v - bf2f(h));
                const int byt = row * 256 + ((col * 2) ^ ((row & 7) << 4));
                *(unsigned short*)((char*)sH[0] + byt) = h;
                *(unsigned short*)((char*)sH[1] + byt) = l;
            }
        __syncthreads();                               // BAR3: sH ready

        // ================= layer 2 =================
        #pragma unroll
        for (int mi = 0; mi < 4; ++mi) acc[mi] = (f32x4){tb2, tb2, tb2, tb2};
        {
            const unsigned short* wlo = wt + 3 * DIM * DIM;        // W2 lo plane
            bf16x8 bl[4];
            #pragma unroll
            for (int kk = 0; kk < 4; ++kk)
                bl[kk] = *(const bf16x8*)(wlo + (cw + l15) * DIM + kk * 32 + g * 8);
            #pragma unroll
            for (int kk = 0; kk < 4; ++kk) {
                const int kb = (kk * 32 + g * 8) * 2;
                #pragma unroll
                for (int mi = 0; mi < 4; ++mi) {
                    const int row = mi * 16 + l15;
                    const int byt = row * 256 + (kb ^ ((row & 7) << 4));
                    const bf16x8 ah = *(const bf16x8*)((const char*)sH[0] + byt);
                    const bf16x8 al = *(const bf16x8*)((const char*)sH[1] + byt);
                    acc[mi] = __builtin_amdgcn_mfma_f32_16x16x32_bf16(ah, bh[1][kk], acc[mi], 0, 0, 0);
                    acc[mi] = __builtin_amdgcn_mfma_f32_16x16x32_bf16(ah, bl[kk],    acc[mi], 0, 0, 0);
                    acc[mi] = __builtin_amdgcn_mfma_f32_16x16x32_bf16(al, bh[1][kk], acc[mi], 0, 0, 0);
                }
            }
        }

        // ---- relu + column sum rows 0..62 (row 63 = pad: mi=3,g=3,r=3) ----
        float cs = 0.f;
        #pragma unroll
        for (int mi = 0; mi < 4; ++mi)
            #pragma unroll
            for (int r = 0; r < 4; ++r)
                if (!(mi == 3 && g == 3 && r == 3))
                    cs += fmaxf(acc[mi][r], 0.f);
        cs += __shfl_xor(cs, 16);
        cs += __shfl_xor(cs, 32);
        if (g == 0) out[(bg + i) * DIM + cw + l15] = cs;
        // loop-around: next stq to sA is safe (all waves passed BAR3 after their sA reads)
    }
}

extern "C" void kernel_launch(void* const* d_in, const int* in_sizes, int n_in,
                              void* d_out, int out_size, void* d_ws, size_t ws_size,
                              hipStream_t stream) {
    const float* embs = (const float*)d_in[0];
    // d_in[1] = batch_idx (int64): deterministic -> unused
    const float* W1   = (const float*)d_in[2];
    const float* b1   = (const float*)d_in[3];
    const float* W2   = (const float*)d_in[4];
    const float* b2   = (const float*)d_in[5];
    float* out        = (float*)d_out;
    unsigned short* wt = (unsigned short*)d_ws;       // 128 KB

    const int nb = in_sizes[0] / (NODES * DIM);       // 4096
    pack_wt<<<256, 128, 0, stream>>>(W1, W2, wt);
    mlp_mfma<<<nb / GB, 512, 0, stream>>>(embs, W1, b1, b2, wt, out);
}